// Round 1
// baseline (140.204 us; speedup 1.0000x reference)
//
#include <hip/hip_runtime.h>
#include <hip/hip_bf16.h>

// Problem constants (match reference)
#define N_OUT_ROWS 250000
#define CIN 32
#define COUT 64
#define KOCT 8
#define KTOT 256                      // KOCT*CIN
#define TILES (N_OUT_ROWS / 16)       // 15625 row-tiles of 16
#define WPB 4                         // waves per block
#define NBLOCKS ((TILES + WPB - 1) / WPB)  // 3907
#define BN_EPS 1e-5f

typedef __attribute__((ext_vector_type(8))) short bf16x8;
typedef __attribute__((ext_vector_type(4))) float f32x4;

static __device__ __forceinline__ unsigned short f2bf(float f) {
  // round-to-nearest-even f32 -> bf16 bits
  union { float f; unsigned u; } v; v.f = f;
  unsigned r = v.u + 0x7FFFu + ((v.u >> 16) & 1u);
  return (unsigned short)(r >> 16);
}

// Fused gather + bf16-MFMA GEMM + BN partial stats.
// Each wave owns one 16-row output tile (16 rows x 64 cols), A fragments are
// gathered DIRECTLY from global (no LDS staging), B (weights) staged once per
// block into LDS as bf16, transposed + XOR-swizzled for conflict-free
// ds_read_b128.
__global__ __launch_bounds__(256, 4)
void k_gemm(const float* __restrict__ x, const int* __restrict__ neigh,
            const float* __restrict__ w, float* __restrict__ out,
            float* __restrict__ stats) {
  __shared__ unsigned short Bt[COUT * KTOT];  // 32 KB, Bt[d][k*32+c] swizzled
  __shared__ float wpart[WPB][128];           // per-wave column partials

  const int tid = threadIdx.x;

  // Stage weights: w flat index i = (k*32+c)*64 + d  ->  Bt[d][kc]
  for (int j = 0; j < 64; ++j) {
    int i = j * 256 + tid;
    int d = i & 63;
    int kc = i >> 6;
    int e = (d << 8) + kc;
    e ^= (d & 7) << 3;  // bank swizzle (element-level; <<4 in bytes)
    Bt[e] = f2bf(w[i]);
  }
  __syncthreads();

  const int lane = tid & 63;
  const int widx = tid >> 6;
  const int tile = blockIdx.x * WPB + widx;
  const int r  = lane & 15;   // A-frag row / B-frag col-within-tile
  const int g4 = lane >> 4;   // k-slice group
  const bool active = tile < TILES;

  f32x4 acc[4];
  #pragma unroll
  for (int ct = 0; ct < 4; ++ct) acc[ct] = (f32x4){0.f, 0.f, 0.f, 0.f};

  if (active) {
    const int n0 = tile << 4;
    const int nrow = n0 + r;
    // 8 neighbor indices for this lane's A-row
    const int4 nv0 = *reinterpret_cast<const int4*>(neigh + nrow * KOCT);
    const int4 nv1 = *reinterpret_cast<const int4*>(neigh + nrow * KOCT + 4);
    int idx[KOCT] = {nv0.x, nv0.y, nv0.z, nv0.w, nv1.x, nv1.y, nv1.z, nv1.w};

    #pragma unroll
    for (int kt = 0; kt < KOCT; ++kt) {
      // lane loads its own A fragment: x[idx[kt]][g4*8 .. g4*8+7]
      const float* xr = x + idx[kt] * CIN + g4 * 8;
      const float4 v0 = *reinterpret_cast<const float4*>(xr);
      const float4 v1 = *reinterpret_cast<const float4*>(xr + 4);
      bf16x8 af;
      af[0] = (short)f2bf(v0.x); af[1] = (short)f2bf(v0.y);
      af[2] = (short)f2bf(v0.z); af[3] = (short)f2bf(v0.w);
      af[4] = (short)f2bf(v1.x); af[5] = (short)f2bf(v1.y);
      af[6] = (short)f2bf(v1.z); af[7] = (short)f2bf(v1.w);
      #pragma unroll
      for (int ct = 0; ct < 4; ++ct) {
        int e = ((ct * 16 + r) << 8) + kt * 32 + g4 * 8;
        e ^= (r & 7) << 3;
        const bf16x8 bfr = *reinterpret_cast<const bf16x8*>(&Bt[e]);
        acc[ct] = __builtin_amdgcn_mfma_f32_16x16x32_bf16(af, bfr, acc[ct], 0, 0, 0);
      }
    }

    // C write: col = ct*16 + (lane&15), row = (lane>>4)*4 + j  (m89-verified)
    const int rbase = n0 + g4 * 4;
    #pragma unroll
    for (int ct = 0; ct < 4; ++ct) {
      #pragma unroll
      for (int j = 0; j < 4; ++j) {
        out[(rbase + j) * COUT + ct * 16 + r] = acc[ct][j];
      }
    }
  }

  // BN partial stats: per-channel sum & sumsq over this wave's 16 rows.
  // Inactive waves contribute zeros (acc stayed zero).
  float s[4], q[4];
  #pragma unroll
  for (int ct = 0; ct < 4; ++ct) {
    s[ct] = acc[ct][0] + acc[ct][1] + acc[ct][2] + acc[ct][3];
    q[ct] = acc[ct][0] * acc[ct][0] + acc[ct][1] * acc[ct][1] +
            acc[ct][2] * acc[ct][2] + acc[ct][3] * acc[ct][3];
    s[ct] += __shfl_xor(s[ct], 16);
    q[ct] += __shfl_xor(q[ct], 16);
    s[ct] += __shfl_xor(s[ct], 32);
    q[ct] += __shfl_xor(q[ct], 32);
  }
  if (lane < 16) {
    #pragma unroll
    for (int ct = 0; ct < 4; ++ct) {
      wpart[widx][ct * 16 + lane] = s[ct];
      wpart[widx][64 + ct * 16 + lane] = q[ct];
    }
  }
  __syncthreads();
  if (tid < 128) {
    float v = wpart[0][tid] + wpart[1][tid] + wpart[2][tid] + wpart[3][tid];
    atomicAdd(&stats[tid], v);
  }
}

// Finalize BN: y = (out - mean) * rsqrt(var+eps) * gamma + beta, in place.
__global__ __launch_bounds__(256)
void k_bn(float* __restrict__ out, const float* __restrict__ stats,
          const float* __restrict__ gamma, const float* __restrict__ beta) {
  __shared__ float sc[COUT], bs[COUT];
  if (threadIdx.x < COUT) {
    const int d = threadIdx.x;
    const float inv = 1.0f / (float)N_OUT_ROWS;
    const float mean = stats[d] * inv;
    const float var = stats[COUT + d] * inv - mean * mean;
    const float rstd = rsqrtf(var + BN_EPS);
    const float scale = rstd * gamma[d];
    sc[d] = scale;
    bs[d] = beta[d] - mean * scale;
  }
  __syncthreads();

  const int total4 = N_OUT_ROWS * COUT / 4;  // 4,000,000 float4s
  float4* o4 = reinterpret_cast<float4*>(out);
  for (int i = blockIdx.x * blockDim.x + threadIdx.x; i < total4;
       i += gridDim.x * blockDim.x) {
    const int d0 = (i & 15) << 2;  // 16 float4 per 64-ch row
    float4 v = o4[i];
    v.x = v.x * sc[d0]     + bs[d0];
    v.y = v.y * sc[d0 + 1] + bs[d0 + 1];
    v.z = v.z * sc[d0 + 2] + bs[d0 + 2];
    v.w = v.w * sc[d0 + 3] + bs[d0 + 3];
    o4[i] = v;
  }
}

extern "C" void kernel_launch(void* const* d_in, const int* in_sizes, int n_in,
                              void* d_out, int out_size, void* d_ws, size_t ws_size,
                              hipStream_t stream) {
  const float* x     = (const float*)d_in[0];
  const int*   neigh = (const int*)d_in[1];
  const float* w     = (const float*)d_in[2];
  const float* gamma = (const float*)d_in[3];
  const float* beta  = (const float*)d_in[4];
  float* out   = (float*)d_out;
  float* stats = (float*)d_ws;  // 128 floats: [0:64] sum, [64:128] sumsq

  hipMemsetAsync(stats, 0, 128 * sizeof(float), stream);
  k_gemm<<<NBLOCKS, 256, 0, stream>>>(x, neigh, w, out, stats);
  k_bn<<<2048, 256, 0, stream>>>(out, stats, gamma, beta);
}